// Round 16
// baseline (199.461 us; speedup 1.0000x reference)
//
#include <hip/hip_runtime.h>
#include <hip/hip_bf16.h>
#include <math.h>

#define THREADS 256
#define WAVES 4
#define NB 8             // batches per block
#define MROWS (NB*9)     // 72 valid rows
#define MT 5             // 5 m-tiles of 16; rows 72..79 dummy

// LDS pool (bytes), total 31232 -> 5 blocks/CU.
// P1 [0,20736): big [80][128] (c3/f1); [80][32] (c1-out/rs) @0..5120, guard @5120
//   c3/f1 guard @20480; wave tail scratch @8192 + wave*1280 (ends 13312)
// P2 [20736,+10496): [80][64] (x/c2/c4flat/f2) @0..10240, guard @10240
//   a1 @0 ([80][16] swz5)
#define P1SZ 20736
#define P2SZ 10496
#define POOLSZ (P1SZ + P2SZ)
#define WS_STRIDE 1280

#define WSYNC() do { __asm__ volatile("s_waitcnt lgkmcnt(0)" ::: "memory"); \
                     __builtin_amdgcn_sched_barrier(0); } while(0)

typedef __attribute__((ext_vector_type(8))) short bf16x8;
typedef __attribute__((ext_vector_type(4))) float f32x4;

__device__ __forceinline__ float leaky(float x){ return fmaxf(x, 0.02f*x); }
__device__ __forceinline__ float fast_tanh(float x){
  float e = __expf(2.f*x);
  return 1.f - 2.f/(e + 1.f);
}

__device__ __forceinline__ unsigned short f2bf(float f){
  union { float f; unsigned u; } v; v.f = f;
  unsigned r = (v.u + 0x7FFFu + ((v.u >> 16) & 1u)) >> 16;
  return (unsigned short)r;
}
__device__ __forceinline__ float bf2f(unsigned short h){
  union { unsigned u; float f; } v; v.u = ((unsigned)h) << 16;
  return v.f;
}
__device__ __forceinline__ unsigned pack2bf(float a, float b){
  float2 t; t.x = a; t.y = b;
  __hip_bfloat162 h = __float22bfloat162_rn(t);
  union { __hip_bfloat162 h; unsigned u; } c; c.h = h;
  return c.u;
}

template<int L2R>
__device__ __forceinline__ unsigned swz(unsigned b){
  if constexpr (L2R < 0) return b;
  else return b ^ (((b >> L2R) & 7u) << 4);
}

__device__ __forceinline__ f32x4 mfma16(bf16x8 a, bf16x8 b, f32x4 c){
  return __builtin_amdgcn_mfma_f32_16x16x32_bf16(a, b, c, 0, 0, 0);
}

// ---- packed weight layout offsets (bf16 elements), 512 per fragment ----
#define WB_C1 0
#define WB_C2 6144
#define WB_C3 12288
#define WB_C4 36864
#define WB_F1 61440
#define WB_F2 69632
#define WB_F3 77824
#define WB_A1 79872
#define WB_A2 81408
#define WB_A3 82432
#define WB_A4 82944
#define WB_A5 83456
#define WP_TOTAL 83968   // elements; *2 = 167936 bytes

__global__ void pack_weights(
    const float* __restrict__ cw1, const float* __restrict__ cw2,
    const float* __restrict__ cw3, const float* __restrict__ cw4,
    const float* __restrict__ fw1, const float* __restrict__ fw2,
    const float* __restrict__ fw3, const float* __restrict__ aw1,
    const float* __restrict__ aw2, const float* __restrict__ aw3,
    const float* __restrict__ aw4, const float* __restrict__ aw5,
    short* __restrict__ wp)
{
  int g = blockIdx.x*256 + threadIdx.x;
  if (g >= WP_TOTAL) return;
  const float* w; int base, l2cp, cinw, cout, KS; bool conv;
  if      (g < WB_C2){ w=cw1; base=WB_C1; l2cp=6; cinw=64;  cout=32;  KS=6;  conv=true; }
  else if (g < WB_C3){ w=cw2; base=WB_C2; l2cp=5; cinw=32;  cout=64;  KS=3;  conv=true; }
  else if (g < WB_C4){ w=cw3; base=WB_C3; l2cp=6; cinw=64;  cout=128; KS=6;  conv=true; }
  else if (g < WB_F1){ w=cw4; base=WB_C4; l2cp=7; cinw=128; cout=64;  KS=12; conv=true; }
  else if (g < WB_F2){ w=fw1; base=WB_F1; l2cp=6; cinw=64;  cout=128; KS=2;  conv=false; }
  else if (g < WB_F3){ w=fw2; base=WB_F2; l2cp=7; cinw=128; cout=64;  KS=4;  conv=false; }
  else if (g < WB_A1){ w=fw3; base=WB_F3; l2cp=6; cinw=64;  cout=32;  KS=2;  conv=false; }
  else if (g < WB_A2){ w=aw1; base=WB_A1; l2cp=5; cinw=32;  cout=16;  KS=3;  conv=true; }
  else if (g < WB_A3){ w=aw2; base=WB_A2; l2cp=4; cinw=16;  cout=8;   KS=2;  conv=true; }
  else if (g < WB_A4){ w=aw3; base=WB_A3; l2cp=3; cinw=8;   cout=4;   KS=1;  conv=true; }
  else if (g < WB_A5){ w=aw4; base=WB_A4; l2cp=3; cinw=4;   cout=2;   KS=1;  conv=true; }
  else               { w=aw5; base=WB_A5; l2cp=3; cinw=2;   cout=1;   KS=1;  conv=true; }
  int local = g - base;
  int frag = local >> 9;
  int lane = (local >> 3) & 63;
  int j    = local & 7;
  int nt = frag / KS, ks = frag - nt*KS;
  int hi = lane >> 4, lo = lane & 15;
  int k = ks*32 + hi*8 + j;
  int n = nt*16 + lo;
  float v = 0.f;
  if (n < cout){
    if (conv){
      int dt = k >> l2cp, ci = k & ((1<<l2cp)-1);
      if (dt < 3 && ci < cinw) v = w[((size_t)n*cinw + ci)*3 + dt];
    } else {
      v = w[(size_t)n*cinw + k];
    }
  }
  wp[g] = (short)f2bf(v);
}

// ---------------- MFMA layer, operand-swapped (D[n][R]), weights preloaded ----------------
template<int CINP, int CINW, int COUT, int STORE_CH, int KS, int MYNT,
         int L2RI, int L2RO, bool IN_CONV, int OUT_MODE, int ACT,
         int LBASE, int GOFF, bool PACKED>
__device__ __forceinline__ void mfma_layer(
    const short* __restrict__ wp, const float* __restrict__ w,
    const float* __restrict__ bias, const char* __restrict__ inb,
    char* __restrict__ outb, int tid)
{
  constexpr int NT = (COUT + 15)/16;
  constexpr int NTG = (NT + MYNT - 1)/MYNT;
  constexpr int L2CINP = (CINP==8?3:CINP==16?4:CINP==32?5:CINP==64?6:7);
  constexpr bool HOIST = (MYNT <= 2);
  const int wave = tid >> 6, lane = tid & 63;
  const int hi = lane >> 4, lo = lane & 15;

  int nt0, mlo, mhi;
  if constexpr (NTG >= WAVES){
    nt0 = (wave % NTG)*MYNT; mlo = 0; mhi = MT;
  } else {
    constexpr int WPN = WAVES/NTG;
    int seg = wave / NTG; int g = wave - seg*NTG;
    nt0 = g*MYNT; mlo = (MT*seg)/WPN; mhi = (MT*(seg+1))/WPN;
  }

  const int k0h = hi*8;

  bf16x8 Bf[MYNT][KS];
  #pragma unroll
  for (int nt = 0; nt < MYNT; ++nt){
    #pragma unroll
    for (int ks = 0; ks < KS; ++ks){
      if constexpr (PACKED){
        Bf[nt][ks] = *(const bf16x8*)(wp + LBASE + (((nt0+nt)*KS + ks) << 9) + lane*8);
      } else {
        bf16x8 r;
        int n = (nt0+nt)*16 + lo;
        #pragma unroll
        for (int j = 0; j < 8; ++j){
          int k = ks*32 + k0h + j;
          float v = 0.f;
          if (n < COUT){
            if constexpr (IN_CONV){
              int dt = k >> L2CINP, ci = k & (CINP-1);
              if (dt < 3 && ci < CINW) v = w[((size_t)n*CINW + ci)*3 + dt];
            } else {
              v = w[(size_t)n*CINP + k];
            }
          }
          r[j] = (short)f2bf(v);
        }
        Bf[nt][ks] = r;
      }
    }
  }

  float bvh[MYNT][4];
  if constexpr (HOIST){
    #pragma unroll
    for (int nt = 0; nt < MYNT; ++nt){
      int n0 = (nt0+nt)*16 + hi*4;
      if constexpr (COUT >= 4){
        if (n0 < COUT){
          const float4 b4 = *(const float4*)(bias + n0);
          bvh[nt][0]=b4.x; bvh[nt][1]=b4.y; bvh[nt][2]=b4.z; bvh[nt][3]=b4.w;
        } else { bvh[nt][0]=bvh[nt][1]=bvh[nt][2]=bvh[nt][3]=0.f; }
      } else {
        #pragma unroll
        for (int r = 0; r < 4; ++r) bvh[nt][r] = (n0 + r < COUT) ? bias[n0+r] : 0.f;
      }
    }
  }

  auto store_out = [&](int nt, const f32x4& a, int R, int bl2, int t2){
    const int n0 = (nt0+nt)*16 + hi*4;
    float bv[4];
    if constexpr (HOIST){
      bv[0]=bvh[nt][0]; bv[1]=bvh[nt][1]; bv[2]=bvh[nt][2]; bv[3]=bvh[nt][3];
    } else {
      if constexpr (COUT >= 4){
        if (n0 < COUT){
          const float4 b4 = *(const float4*)(bias + n0);
          bv[0]=b4.x; bv[1]=b4.y; bv[2]=b4.z; bv[3]=b4.w;
        } else { bv[0]=bv[1]=bv[2]=bv[3]=0.f; }
      } else {
        #pragma unroll
        for (int r = 0; r < 4; ++r) bv[r] = (n0 + r < COUT) ? bias[n0+r] : 0.f;
      }
    }
    if constexpr (OUT_MODE == 2){
      if (R < MROWS){
        #pragma unroll
        for (int r = 0; r < 4; ++r){
          float vr = leaky(a[r] + bv[r]);
          unsigned byte = (unsigned)((bl2*576 + (n0+r)*9 + t2)*2);
          *(short*)(outb + swz<L2RO>(byte)) = (short)f2bf(vr);
        }
      }
    } else {
      if (n0 < STORE_CH){
        float v[4];
        #pragma unroll
        for (int r = 0; r < 4; ++r){
          float vr0 = a[r] + bv[r];
          float vr = (ACT==0) ? leaky(vr0) : fast_tanh(vr0);
          if constexpr (STORE_CH > COUT){ if (n0 + r >= COUT) vr = 0.f; }
          v[r] = vr;
        }
        unsigned byte = (unsigned)R*(unsigned)(STORE_CH*2) + (unsigned)(n0*2);
        uint2 pk; pk.x = pack2bf(v[0], v[1]); pk.y = pack2bf(v[2], v[3]);
        *(uint2*)(outb + swz<L2RO>(byte)) = pk;
      }
    }
  };

  for (int m = mlo; m < mhi; ++m){
    int R = m*16 + lo;
    int bl2 = (int)((unsigned)R/9u);
    int tl = R - bl2*9;

    f32x4 acc[MYNT];
    #pragma unroll
    for (int nt = 0; nt < MYNT; ++nt)
      acc[nt] = (f32x4){0.f, 0.f, 0.f, 0.f};

    #pragma unroll
    for (int ks = 0; ks < KS; ++ks){
      bf16x8 Af;
      if constexpr (IN_CONV){
        int k0 = ks*32 + k0h;
        int dtv = k0 >> L2CINP;
        unsigned ra = swz<L2RI>((unsigned)(((R-1)*CINP + k0) << 1));
        bool ok = ((unsigned)(tl + dtv - 1) < 9u) && (dtv < 3);
        unsigned addr = ok ? ra : (unsigned)GOFF;
        Af = *(const bf16x8*)(inb + addr);
      } else {
        unsigned byte0 = (unsigned)((R*CINP + ks*32 + k0h) << 1);
        Af = *(const bf16x8*)(inb + swz<L2RI>(byte0));
      }
      #pragma unroll
      for (int nt = 0; nt < MYNT; ++nt)
        acc[nt] = mfma16(Bf[nt][ks], Af, acc[nt]);   // SWAPPED: D[n][R]
    }
    #pragma unroll
    for (int nt = 0; nt < MYNT; ++nt) store_out(nt, acc[nt], R, bl2, tl);
  }
}

// small VALU conv stage for the wave-private tail
// in: LDS padded [2][11][CIN] bf16 at inp (t stored t+1, pads zero)
// out: same style [2][11][COUT] at outp. Lanes: (b=lane>>5, co=(l5>>2), tg=(l5&3)),
// active when l5 < COUT*4.
template<int CIN, int COUT>
__device__ __forceinline__ void tail_conv(const float* __restrict__ w,
    const float* __restrict__ bias, const char* inp, char* outp, int lane)
{
  const int b = lane >> 5, l5 = lane & 31;
  const int co = l5 >> 2, tg = l5 & 3;
  if (l5 < COUT*4){
    int tstart = (tg==0) ? 0 : (2*tg+1);
    int tcnt   = (tg==0) ? 3 : 2;
    float bv = bias[co];
    float acc[3]; acc[0]=bv; acc[1]=bv; acc[2]=bv;
    for (int ci = 0; ci < CIN; ++ci){
      float tap[5];
      #pragma unroll
      for (int k = 0; k < 5; ++k){
        float v = 0.f;
        if (k < tcnt + 2){
          int idx = tstart + k;               // padded row index (t+1 space), in [0,10]
          v = bf2f(*(const unsigned short*)(inp + (b*11*CIN + idx*CIN + ci)*2));
        }
        tap[k] = v;
      }
      const float* wq = w + (co*CIN + ci)*3;
      float w0 = wq[0], w1 = wq[1], w2 = wq[2];
      #pragma unroll
      for (int j = 0; j < 3; ++j)
        acc[j] = fmaf(w0, tap[j], fmaf(w1, tap[j+1], fmaf(w2, tap[j+2], acc[j])));
    }
    #pragma unroll
    for (int j = 0; j < 3; ++j){
      if (j < tcnt){
        int t = tstart + j;
        *(short*)(outp + (b*11*COUT + (t+1)*COUT + co)*2) = (short)f2bf(leaky(acc[j]));
      }
    }
  }
}

template<bool PACKED>
__global__ __launch_bounds__(THREADS, 5)
void fused_expr_kernel(
    const float* __restrict__ x, const int* __restrict__ ident,
    const float* __restrict__ cw1, const float* __restrict__ cb1,
    const float* __restrict__ cw2, const float* __restrict__ cb2,
    const float* __restrict__ cw3, const float* __restrict__ cb3,
    const float* __restrict__ cw4, const float* __restrict__ cb4,
    const float* __restrict__ fw1, const float* __restrict__ fb1,
    const float* __restrict__ fw2, const float* __restrict__ fb2,
    const float* __restrict__ fw3, const float* __restrict__ fb3,
    const float* __restrict__ aw1, const float* __restrict__ ab1,
    const float* __restrict__ aw2, const float* __restrict__ ab2,
    const float* __restrict__ aw3, const float* __restrict__ ab3,
    const float* __restrict__ aw4, const float* __restrict__ ab4,
    const float* __restrict__ aw5, const float* __restrict__ ab5,
    const float* __restrict__ lw,  const float* __restrict__ lb,
    const float* __restrict__ mapping, const short* __restrict__ wp,
    float* __restrict__ out)
{
  __shared__ __align__(16) char pool[POOLSZ];

  char* P1 = pool;
  char* P2 = pool + P1SZ;

  const int tid = threadIdx.x;
  const int b0 = blockIdx.x * NB;

  const uint2 z2 = {0u, 0u};

  // ---- stage x (fp32, (B,9,64)) -> P2 bf16 flat [72][64] swz<7>; zero dummies + guards
  {
    const float4* xb4 = (const float4*)(x + (size_t)b0 * 576);
    for (int i = tid; i < NB*144; i += THREADS){
      int b = i / 144; int rem = i - b*144;     // rem = t*16 + c4
      int t = rem >> 4; int c4 = rem & 15;
      float4 v = xb4[i];
      uint2 pk;
      pk.x = pack2bf(v.x, v.y);
      pk.y = pack2bf(v.z, v.w);
      unsigned byte = (unsigned)(((b*9 + t)*64 + c4*4)*2);
      *(uint2*)(P2 + swz<7>(byte)) = pk;
    }
    for (int i = tid; i < 128; i += THREADS){   // dummy rows 72..79 of x
      int rr = 72 + (i >> 4); int c4 = i & 15;
      unsigned byte = (unsigned)((rr*64 + c4*4)*2);
      *(uint2*)(P2 + swz<7>(byte)) = z2;
    }
    if (tid < 12){
      int g = tid >> 2, o = (tid & 3)*8;
      char* dst = (g==0) ? (P2 + 10240 + o) : (g==1) ? (P1 + 5120 + o) : (P1 + 20480 + o);
      *(uint2*)dst = z2;
    }
  }
  __syncthreads();

  //          CINP CINW COUT  SC  KS MYNT LI LO  CONV  OM ACT  LBASE  GOFF(in)
  mfma_layer<64, 64, 32, 32, 6, 1, 7, 6, true, 0, 0, WB_C1, 10240, PACKED>(wp, cw1, cb1, P2, P1, tid); __syncthreads();
  mfma_layer<32, 32, 64, 64, 3, 2, 6, 7, true, 0, 0, WB_C2, 5120,  PACKED>(wp, cw2, cb2, P1, P2, tid); __syncthreads();
  mfma_layer<64, 64,128,128, 6, 2, 7, 8, true, 0, 0, WB_C3, 10240, PACKED>(wp, cw3, cb3, P2, P1, tid); __syncthreads();
  mfma_layer<128,128,64, 64,12, 1, 8, 7, true, 2, 0, WB_C4, 20480, PACKED>(wp, cw4, cb4, P1, P2, tid); __syncthreads(); // conv4-flat [bl][576]
  mfma_layer<64, 64,128,128, 2, 4, 7, 8, false,0, 0, WB_F1, 0,     PACKED>(wp, fw1, fb1, P2, P1, tid); __syncthreads(); // [R][128]
  mfma_layer<128,128,64, 64, 4, 2, 8, 7, false,0, 0, WB_F2, 0,     PACKED>(wp, fw2, fb2, P1, P2, tid); __syncthreads(); // [R][64]
  mfma_layer<64, 64, 32, 32, 2, 2, 7, 6, false,0, 1, WB_F3, 0,     PACKED>(wp, fw3, fb3, P2, P1, tid);                  // rs [R][32]
  if (tid < 4) *(uint2*)(P1 + 5120 + tid*8) = z2;   // re-zero rs guard (f1 clobbered it)
  __syncthreads();

  char* rs = P1;               // [80][32] swz6
  char* a1 = P2;               // [80][16] swz5

  mfma_layer<32, 32, 16, 16, 3, 1, 6, 5, true, 0, 0, WB_A1, 5120, PACKED>(wp, aw1, ab1, rs, a1, tid);
  __syncthreads();             // last block-wide barrier

  // ============ wave-private tail: a2..a5, logits, softmax, sub, out ============
  {
    const int lane = tid & 63;
    const int wave = tid >> 6;
    const int b_loc = lane >> 5;          // 0..1
    const int l5 = lane & 31;
    const int bg = wave*2 + b_loc;        // batch in block, 0..7
    const int rowb = bg*9;

    char* ws = P1 + 8192 + wave*WS_STRIDE;
    char* a2s = ws;                       // [2][11][8] bf16
    char* a3s = ws + 384;                 // [2][11][4]
    char* a4s = ws + 576;                 // [2][11][2]
    char* a5s = ws + 672;                 // [2][11]
    float* lg  = (float*)(ws + 720);      // [2][9]
    float* att = (float*)(ws + 800);      // [2][9]
    float* subs= (float*)(ws + 896);      // [2][32]

    for (int i = lane; i < WS_STRIDE/4; i += 64) ((unsigned*)ws)[i] = 0u;
    WSYNC();

    // ---- a2: 16 -> 8 (reads block-level a1, unpadded rows, swz5) ----
    {
      const int co = l5 >> 2, tg = l5 & 3;
      int tstart = (tg==0) ? 0 : (2*tg+1);
      int tcnt   = (tg==0) ? 3 : 2;
      float bv = ab2[co];
      float acc[3]; acc[0]=bv; acc[1]=bv; acc[2]=bv;
      for (int ci = 0; ci < 16; ++ci){
        float tap[5];
        #pragma unroll
        for (int k = 0; k < 5; ++k){
          int tt = tstart - 1 + k;
          float v = 0.f;
          if (k < tcnt + 2 && (unsigned)tt < 9u){
            unsigned byte = (unsigned)(((rowb + tt)*16 + ci)*2);
            v = bf2f(*(const unsigned short*)(a1 + swz<5>(byte)));
          }
          tap[k] = v;
        }
        const float* wq = aw2 + (co*16 + ci)*3;
        float w0 = wq[0], w1 = wq[1], w2 = wq[2];
        #pragma unroll
        for (int j = 0; j < 3; ++j)
          acc[j] = fmaf(w0, tap[j], fmaf(w1, tap[j+1], fmaf(w2, tap[j+2], acc[j])));
      }
      #pragma unroll
      for (int j = 0; j < 3; ++j){
        if (j < tcnt){
          int t = tstart + j;
          *(short*)(a2s + (b_loc*88 + (t+1)*8 + co)*2) = (short)f2bf(leaky(acc[j]));
        }
      }
    }
    WSYNC();

    tail_conv<8, 4>(aw3, ab3, a2s, a3s, lane);
    WSYNC();
    tail_conv<4, 2>(aw4, ab4, a3s, a4s, lane);
    WSYNC();
    tail_conv<2, 1>(aw5, ab5, a4s, a5s, lane);
    WSYNC();

    // logits: lanes l5<9 per batch
    if (l5 < 9){
      int o = l5;
      float acc = lb[o];
      #pragma unroll
      for (int t = 0; t < 9; ++t)
        acc = fmaf(lw[o*9 + t], bf2f(*(const unsigned short*)(a5s + (b_loc*11 + t+1)*2)), acc);
      lg[b_loc*9 + o] = acc;
    }
    WSYNC();

    // softmax: one lane per batch
    if (l5 == 0){
      float m = -1e30f;
      #pragma unroll
      for (int t = 0; t < 9; ++t) m = fmaxf(m, lg[b_loc*9 + t]);
      float s = 0.f, ex[9];
      #pragma unroll
      for (int t = 0; t < 9; ++t){ ex[t] = __expf(lg[b_loc*9 + t] - m); s += ex[t]; }
      float inv = 1.f / s;
      #pragma unroll
      for (int t = 0; t < 9; ++t) att[b_loc*9 + t] = ex[t]*inv;
    }
    WSYNC();

    // sub[b][s], s = l5 (all 64 lanes)
    {
      float acc = 0.f;
      #pragma unroll
      for (int t = 0; t < 9; ++t){
        unsigned byte = (unsigned)(((rowb + t)*32 + l5)*2);
        acc = fmaf(bf2f(*(const unsigned short*)(rs + swz<6>(byte))), att[b_loc*9 + t], acc);
      }
      subs[b_loc*32 + l5] = acc;
    }
    WSYNC();

    // out[b][e] = 10 * sum_s mapping[id][e][s] * sub[b][s]
    {
      float sv[32];
      const float4* sp4 = (const float4*)(subs + b_loc*32);
      #pragma unroll
      for (int q = 0; q < 8; ++q){
        float4 v = sp4[q];
        sv[q*4+0]=v.x; sv[q*4+1]=v.y; sv[q*4+2]=v.z; sv[q*4+3]=v.w;
      }
      const int b = b0 + bg;
      const size_t id = (size_t)ident[b];
      const float* mb = mapping + id*53*32;
      #pragma unroll
      for (int h = 0; h < 2; ++h){
        int e = h*32 + l5;
        if (e < 53){
          const float4* mrow4 = (const float4*)(mb + e*32);
          float acc = 0.f;
          #pragma unroll
          for (int s4 = 0; s4 < 8; ++s4){
            float4 mv = mrow4[s4];
            acc = fmaf(mv.x, sv[s4*4+0], acc);
            acc = fmaf(mv.y, sv[s4*4+1], acc);
            acc = fmaf(mv.z, sv[s4*4+2], acc);
            acc = fmaf(mv.w, sv[s4*4+3], acc);
          }
          out[(size_t)b*53 + e] = 10.f*acc;
        }
      }
    }
  }
}

extern "C" void kernel_launch(void* const* d_in, const int* in_sizes, int n_in,
                              void* d_out, int out_size, void* d_ws, size_t ws_size,
                              hipStream_t stream) {
  const float* x    = (const float*)d_in[0];
  const int*   ident= (const int*)  d_in[1];
  const float* cw1  = (const float*)d_in[2];  const float* cb1 = (const float*)d_in[3];
  const float* cw2  = (const float*)d_in[4];  const float* cb2 = (const float*)d_in[5];
  const float* cw3  = (const float*)d_in[6];  const float* cb3 = (const float*)d_in[7];
  const float* cw4  = (const float*)d_in[8];  const float* cb4 = (const float*)d_in[9];
  const float* fw1  = (const float*)d_in[10]; const float* fb1 = (const float*)d_in[11];
  const float* fw2  = (const float*)d_in[12]; const float* fb2 = (const float*)d_in[13];
  const float* fw3  = (const float*)d_in[14]; const float* fb3 = (const float*)d_in[15];
  const float* aw1  = (const float*)d_in[16]; const float* ab1 = (const float*)d_in[17];
  const float* aw2  = (const float*)d_in[18]; const float* ab2 = (const float*)d_in[19];
  const float* aw3  = (const float*)d_in[20]; const float* ab3 = (const float*)d_in[21];
  const float* aw4  = (const float*)d_in[22]; const float* ab4 = (const float*)d_in[23];
  const float* aw5  = (const float*)d_in[24]; const float* ab5 = (const float*)d_in[25];
  const float* lw   = (const float*)d_in[26]; const float* lb  = (const float*)d_in[27];
  const float* mapping = (const float*)d_in[28];

  const int B = 32768;
  dim3 grid(B / NB), block(THREADS);

  const bool packed = ws_size >= (size_t)(WP_TOTAL * 2);
  short* wpk = (short*)d_ws;

  if (packed){
    pack_weights<<<dim3(WP_TOTAL/256), dim3(256), 0, stream>>>(
        cw1, cw2, cw3, cw4, fw1, fw2, fw3, aw1, aw2, aw3, aw4, aw5, wpk);
    fused_expr_kernel<true><<<grid, block, 0, stream>>>(
        x, ident, cw1, cb1, cw2, cb2, cw3, cb3, cw4, cb4,
        fw1, fb1, fw2, fb2, fw3, fb3,
        aw1, ab1, aw2, ab2, aw3, ab3, aw4, ab4, aw5, ab5,
        lw, lb, mapping, wpk, (float*)d_out);
  } else {
    fused_expr_kernel<false><<<grid, block, 0, stream>>>(
        x, ident, cw1, cb1, cw2, cb2, cw3, cb3, cw4, cb4,
        fw1, fb1, fw2, fb2, fw3, fb3,
        aw1, ab1, aw2, ab2, aw3, ab3, aw4, ab4, aw5, ab5,
        lw, lb, mapping, wpk, (float*)d_out);
  }
}

// Round 17
// 130.874 us; speedup vs baseline: 1.5241x; 1.5241x over previous
//
#include <hip/hip_runtime.h>
#include <hip/hip_bf16.h>
#include <math.h>

#define THREADS 256
#define WAVES 4
#define NB 8             // batches per block
#define MROWS (NB*9)     // 72 valid rows
#define MT 5             // 5 m-tiles of 16; rows 72..79 dummy

// LDS pool (bytes), total 31232 -> 5 blocks/CU.
#define P1SZ 20736
#define P2SZ 10496
#define POOLSZ (P1SZ + P2SZ)

typedef __attribute__((ext_vector_type(8))) short bf16x8;
typedef __attribute__((ext_vector_type(4))) float f32x4;

__device__ __forceinline__ float leaky(float x){ return fmaxf(x, 0.02f*x); }
__device__ __forceinline__ float fast_tanh(float x){
  float e = __expf(2.f*x);
  return 1.f - 2.f/(e + 1.f);
}

__device__ __forceinline__ unsigned short f2bf(float f){
  union { float f; unsigned u; } v; v.f = f;
  unsigned r = (v.u + 0x7FFFu + ((v.u >> 16) & 1u)) >> 16;
  return (unsigned short)r;
}
__device__ __forceinline__ float bf2f(unsigned short h){
  union { unsigned u; float f; } v; v.u = ((unsigned)h) << 16;
  return v.f;
}
__device__ __forceinline__ unsigned pack2bf(float a, float b){
  float2 t; t.x = a; t.y = b;
  __hip_bfloat162 h = __float22bfloat162_rn(t);
  union { __hip_bfloat162 h; unsigned u; } c; c.h = h;
  return c.u;
}

template<int L2R>
__device__ __forceinline__ unsigned swz(unsigned b){
  if constexpr (L2R < 0) return b;
  else return b ^ (((b >> L2R) & 7u) << 4);
}

__device__ __forceinline__ f32x4 mfma16(bf16x8 a, bf16x8 b, f32x4 c){
  return __builtin_amdgcn_mfma_f32_16x16x32_bf16(a, b, c, 0, 0, 0);
}

// ---- packed weight layout offsets (bf16 elements), 512 per fragment ----
#define WB_C1 0
#define WB_C2 6144
#define WB_C3 12288
#define WB_C4 36864
#define WB_F1 61440
#define WB_F2 69632
#define WB_F3 77824
#define WB_A1 79872
#define WB_A2 81408
#define WB_A3 82432
#define WB_A4 82944
#define WB_A5 83456
#define WP_TOTAL 83968   // elements; *2 = 167936 bytes

__global__ void pack_weights(
    const float* __restrict__ cw1, const float* __restrict__ cw2,
    const float* __restrict__ cw3, const float* __restrict__ cw4,
    const float* __restrict__ fw1, const float* __restrict__ fw2,
    const float* __restrict__ fw3, const float* __restrict__ aw1,
    const float* __restrict__ aw2, const float* __restrict__ aw3,
    const float* __restrict__ aw4, const float* __restrict__ aw5,
    short* __restrict__ wp)
{
  int g = blockIdx.x*256 + threadIdx.x;
  if (g >= WP_TOTAL) return;
  const float* w; int base, l2cp, cinw, cout, KS; bool conv;
  if      (g < WB_C2){ w=cw1; base=WB_C1; l2cp=6; cinw=64;  cout=32;  KS=6;  conv=true; }
  else if (g < WB_C3){ w=cw2; base=WB_C2; l2cp=5; cinw=32;  cout=64;  KS=3;  conv=true; }
  else if (g < WB_C4){ w=cw3; base=WB_C3; l2cp=6; cinw=64;  cout=128; KS=6;  conv=true; }
  else if (g < WB_F1){ w=cw4; base=WB_C4; l2cp=7; cinw=128; cout=64;  KS=12; conv=true; }
  else if (g < WB_F2){ w=fw1; base=WB_F1; l2cp=6; cinw=64;  cout=128; KS=2;  conv=false; }
  else if (g < WB_F3){ w=fw2; base=WB_F2; l2cp=7; cinw=128; cout=64;  KS=4;  conv=false; }
  else if (g < WB_A1){ w=fw3; base=WB_F3; l2cp=6; cinw=64;  cout=32;  KS=2;  conv=false; }
  else if (g < WB_A2){ w=aw1; base=WB_A1; l2cp=5; cinw=32;  cout=16;  KS=3;  conv=true; }
  else if (g < WB_A3){ w=aw2; base=WB_A2; l2cp=4; cinw=16;  cout=8;   KS=2;  conv=true; }
  else if (g < WB_A4){ w=aw3; base=WB_A3; l2cp=3; cinw=8;   cout=4;   KS=1;  conv=true; }
  else if (g < WB_A5){ w=aw4; base=WB_A4; l2cp=3; cinw=4;   cout=2;   KS=1;  conv=true; }
  else               { w=aw5; base=WB_A5; l2cp=3; cinw=2;   cout=1;   KS=1;  conv=true; }
  int local = g - base;
  int frag = local >> 9;
  int lane = (local >> 3) & 63;
  int j    = local & 7;
  int nt = frag / KS, ks = frag - nt*KS;
  int hi = lane >> 4, lo = lane & 15;
  int k = ks*32 + hi*8 + j;
  int n = nt*16 + lo;
  float v = 0.f;
  if (n < cout){
    if (conv){
      int dt = k >> l2cp, ci = k & ((1<<l2cp)-1);
      if (dt < 3 && ci < cinw) v = w[((size_t)n*cinw + ci)*3 + dt];
    } else {
      v = w[(size_t)n*cinw + k];
    }
  }
  wp[g] = (short)f2bf(v);
}

// ---------------- MFMA layer, operand-swapped (D[n][R]), all weights preloaded ----------------
// Input flat [R][CINP] (80 rows incl. dummies). Conv tap element (R-1)*CINP + k,
// invalid taps redirected branch-free to zeroed guard at byte GOFF.
// OUT_MODE: 0 flat [R][STORE_CH]; 2 conv4-flat [bl][576] (c*9+t, R<MROWS only);
// 3 single-channel flat [R]. ACT: 0 leaky, 1 tanh.
template<int CINP, int CINW, int COUT, int STORE_CH, int KS, int MYNT,
         int L2RI, int L2RO, bool IN_CONV, int OUT_MODE, int ACT,
         int LBASE, int GOFF, bool PACKED>
__device__ __forceinline__ void mfma_layer(
    const short* __restrict__ wp, const float* __restrict__ w,
    const float* __restrict__ bias, const char* __restrict__ inb,
    char* __restrict__ outb, int tid)
{
  constexpr int NT = (COUT + 15)/16;
  constexpr int NTG = (NT + MYNT - 1)/MYNT;
  constexpr int L2CINP = (CINP==8?3:CINP==16?4:CINP==32?5:CINP==64?6:7);
  constexpr bool HOIST = (MYNT <= 2);   // preload bias; skipped for fat MYNT to protect live-set
  const int wave = tid >> 6, lane = tid & 63;
  const int hi = lane >> 4, lo = lane & 15;

  int nt0, mlo, mhi;
  if constexpr (NTG >= WAVES){
    nt0 = (wave % NTG)*MYNT; mlo = 0; mhi = MT;
  } else {
    constexpr int WPN = WAVES/NTG;
    int seg = wave / NTG; int g = wave - seg*NTG;
    nt0 = g*MYNT; mlo = (MT*seg)/WPN; mhi = (MT*(seg+1))/WPN;
  }

  const int k0h = hi*8;

  // preload all B fragments (weights, A-role in swapped mfma)
  bf16x8 Bf[MYNT][KS];
  #pragma unroll
  for (int nt = 0; nt < MYNT; ++nt){
    #pragma unroll
    for (int ks = 0; ks < KS; ++ks){
      if constexpr (PACKED){
        Bf[nt][ks] = *(const bf16x8*)(wp + LBASE + (((nt0+nt)*KS + ks) << 9) + lane*8);
      } else {
        bf16x8 r;
        int n = (nt0+nt)*16 + lo;
        #pragma unroll
        for (int j = 0; j < 8; ++j){
          int k = ks*32 + k0h + j;
          float v = 0.f;
          if (n < COUT){
            if constexpr (IN_CONV){
              int dt = k >> L2CINP, ci = k & (CINP-1);
              if (dt < 3 && ci < CINW) v = w[((size_t)n*CINW + ci)*3 + dt];
            } else {
              v = w[(size_t)n*CINP + k];
            }
          }
          r[j] = (short)f2bf(v);
        }
        Bf[nt][ks] = r;
      }
    }
  }

  // bias (hoisted out of the m-loop when register budget allows)
  float bvh[MYNT][4];
  if constexpr (HOIST){
    #pragma unroll
    for (int nt = 0; nt < MYNT; ++nt){
      int n0 = (nt0+nt)*16 + hi*4;
      if constexpr (COUT >= 4){
        if (n0 < COUT){
          const float4 b4 = *(const float4*)(bias + n0);
          bvh[nt][0]=b4.x; bvh[nt][1]=b4.y; bvh[nt][2]=b4.z; bvh[nt][3]=b4.w;
        } else { bvh[nt][0]=bvh[nt][1]=bvh[nt][2]=bvh[nt][3]=0.f; }
      } else {
        #pragma unroll
        for (int r = 0; r < 4; ++r) bvh[nt][r] = (n0 + r < COUT) ? bias[n0+r] : 0.f;
      }
    }
  }

  auto store_out = [&](int nt, const f32x4& a, int R, int bl2, int t2){
    const int n0 = (nt0+nt)*16 + hi*4;
    float bv[4];
    if constexpr (HOIST){
      bv[0]=bvh[nt][0]; bv[1]=bvh[nt][1]; bv[2]=bvh[nt][2]; bv[3]=bvh[nt][3];
    } else {
      if constexpr (COUT >= 4){
        if (n0 < COUT){
          const float4 b4 = *(const float4*)(bias + n0);
          bv[0]=b4.x; bv[1]=b4.y; bv[2]=b4.z; bv[3]=b4.w;
        } else { bv[0]=bv[1]=bv[2]=bv[3]=0.f; }
      } else {
        #pragma unroll
        for (int r = 0; r < 4; ++r) bv[r] = (n0 + r < COUT) ? bias[n0+r] : 0.f;
      }
    }
    if constexpr (OUT_MODE == 2){
      if (R < MROWS){
        #pragma unroll
        for (int r = 0; r < 4; ++r){
          float vr = leaky(a[r] + bv[r]);
          unsigned byte = (unsigned)((bl2*576 + (n0+r)*9 + t2)*2);
          *(short*)(outb + swz<L2RO>(byte)) = (short)f2bf(vr);
        }
      }
    } else if constexpr (OUT_MODE == 3){
      if (hi == 0){
        float vr0 = a[0] + bv[0];
        float vr = (ACT==0) ? leaky(vr0) : fast_tanh(vr0);
        *(short*)(outb + (unsigned)(R*2)) = (short)f2bf(vr);
      }
    } else {
      if (n0 < STORE_CH){
        float v[4];
        #pragma unroll
        for (int r = 0; r < 4; ++r){
          float vr0 = a[r] + bv[r];
          float vr = (ACT==0) ? leaky(vr0) : fast_tanh(vr0);
          if constexpr (STORE_CH > COUT){ if (n0 + r >= COUT) vr = 0.f; }
          v[r] = vr;
        }
        unsigned byte = (unsigned)R*(unsigned)(STORE_CH*2) + (unsigned)(n0*2);
        uint2 pk; pk.x = pack2bf(v[0], v[1]); pk.y = pack2bf(v[2], v[3]);
        *(uint2*)(outb + swz<L2RO>(byte)) = pk;
      }
    }
  };

  for (int m = mlo; m < mhi; ++m){
    int R = m*16 + lo;
    int bl2 = (int)((unsigned)R/9u);
    int tl = R - bl2*9;

    f32x4 acc[MYNT];
    #pragma unroll
    for (int nt = 0; nt < MYNT; ++nt)
      acc[nt] = (f32x4){0.f, 0.f, 0.f, 0.f};

    #pragma unroll
    for (int ks = 0; ks < KS; ++ks){
      bf16x8 Af;
      if constexpr (IN_CONV){
        int k0 = ks*32 + k0h;
        int dtv = k0 >> L2CINP;
        unsigned ra = swz<L2RI>((unsigned)(((R-1)*CINP + k0) << 1));
        bool ok = ((unsigned)(tl + dtv - 1) < 9u) && (dtv < 3);
        unsigned addr = ok ? ra : (unsigned)GOFF;
        Af = *(const bf16x8*)(inb + addr);
      } else {
        unsigned byte0 = (unsigned)((R*CINP + ks*32 + k0h) << 1);
        Af = *(const bf16x8*)(inb + swz<L2RI>(byte0));
      }
      #pragma unroll
      for (int nt = 0; nt < MYNT; ++nt)
        acc[nt] = mfma16(Bf[nt][ks], Af, acc[nt]);   // SWAPPED: D[n][R]
    }
    #pragma unroll
    for (int nt = 0; nt < MYNT; ++nt) store_out(nt, acc[nt], R, bl2, tl);
  }
}

template<bool PACKED>
__global__ __launch_bounds__(THREADS, 5)
void fused_expr_kernel(
    const float* __restrict__ x, const int* __restrict__ ident,
    const float* __restrict__ cw1, const float* __restrict__ cb1,
    const float* __restrict__ cw2, const float* __restrict__ cb2,
    const float* __restrict__ cw3, const float* __restrict__ cb3,
    const float* __restrict__ cw4, const float* __restrict__ cb4,
    const float* __restrict__ fw1, const float* __restrict__ fb1,
    const float* __restrict__ fw2, const float* __restrict__ fb2,
    const float* __restrict__ fw3, const float* __restrict__ fb3,
    const float* __restrict__ aw1, const float* __restrict__ ab1,
    const float* __restrict__ aw2, const float* __restrict__ ab2,
    const float* __restrict__ aw3, const float* __restrict__ ab3,
    const float* __restrict__ aw4, const float* __restrict__ ab4,
    const float* __restrict__ aw5, const float* __restrict__ ab5,
    const float* __restrict__ lw,  const float* __restrict__ lb,
    const float* __restrict__ mapping, const short* __restrict__ wp,
    float* __restrict__ out)
{
  __shared__ __align__(16) char pool[POOLSZ];

  char* P1 = pool;
  char* P2 = pool + P1SZ;

  float* logits_s = (float*)(P2 + 7168);   // [NB*9]
  float* att_s    = (float*)(P2 + 7456);   // [NB*9]
  float* sub_s    = (float*)(P2 + 7744);   // [NB*32]

  const int tid = threadIdx.x;
  const int b0 = blockIdx.x * NB;
  const int p  = tid >> 3;    // 0..31
  const int bl = tid & 7;     // 0..7

  const uint2 z2 = {0u, 0u};

  // ---- stage x (fp32, (B,9,64)) -> P2 bf16 flat [72][64] swz<7>; zero dummy rows + guards
  {
    const float4* xb4 = (const float4*)(x + (size_t)b0 * 576);
    for (int i = tid; i < NB*144; i += THREADS){
      int b = i / 144; int rem = i - b*144;     // rem = t*16 + c4
      int t = rem >> 4; int c4 = rem & 15;
      float4 v = xb4[i];
      uint2 pk;
      pk.x = pack2bf(v.x, v.y);
      pk.y = pack2bf(v.z, v.w);
      unsigned byte = (unsigned)(((b*9 + t)*64 + c4*4)*2);
      *(uint2*)(P2 + swz<7>(byte)) = pk;
    }
    for (int i = tid; i < 128; i += THREADS){   // dummy rows 72..79 of x
      int rr = 72 + (i >> 4); int c4 = i & 15;
      unsigned byte = (unsigned)((rr*64 + c4*4)*2);
      *(uint2*)(P2 + swz<7>(byte)) = z2;
    }
    if (tid < 12){
      int g = tid >> 2, o = (tid & 3)*8;
      char* dst = (g==0) ? (P2 + 10240 + o) : (g==1) ? (P1 + 5120 + o) : (P1 + 20480 + o);
      *(uint2*)dst = z2;
    }
  }
  __syncthreads();

  //          CINP CINW COUT  SC  KS MYNT LI LO  CONV  OM ACT  LBASE  GOFF(in)
  mfma_layer<64, 64, 32, 32, 6, 1, 7, 6, true, 0, 0, WB_C1, 10240, PACKED>(wp, cw1, cb1, P2, P1, tid); __syncthreads();
  mfma_layer<32, 32, 64, 64, 3, 2, 6, 7, true, 0, 0, WB_C2, 5120,  PACKED>(wp, cw2, cb2, P1, P2, tid); __syncthreads();
  mfma_layer<64, 64,128,128, 6, 2, 7, 8, true, 0, 0, WB_C3, 10240, PACKED>(wp, cw3, cb3, P2, P1, tid); __syncthreads();
  mfma_layer<128,128,64, 64,12, 1, 8, 7, true, 2, 0, WB_C4, 20480, PACKED>(wp, cw4, cb4, P1, P2, tid); __syncthreads(); // conv4-flat [bl][576]
  mfma_layer<64, 64,128,128, 2, 4, 7, 8, false,0, 0, WB_F1, 0,     PACKED>(wp, fw1, fb1, P2, P1, tid); __syncthreads(); // [R][128]
  mfma_layer<128,128,64, 64, 4, 2, 8, 7, false,0, 0, WB_F2, 0,     PACKED>(wp, fw2, fb2, P1, P2, tid); __syncthreads(); // [R][64]
  mfma_layer<64, 64, 32, 32, 2, 2, 7, 6, false,0, 1, WB_F3, 0,     PACKED>(wp, fw3, fb3, P2, P1, tid);                  // rs [R][32]
  if (tid < 4) *(uint2*)(P1 + 5120 + tid*8) = z2;   // re-zero rs guard (f1 clobbered it)
  __syncthreads();

  char* rs = P1;               // [80][32] swz6, live until the end
  char* a1 = P2;               // [80][16] swz5, guard @+2560
  char* a2 = P1 + 8192;        // [80][8],  guard @+1280
  char* a3 = P2 + 4096;        // [80][8],  guard @+1280
  char* a4 = P1 + 12288;       // [80][8],  guard @+1280
  char* a5 = P2 + 6144;        // [80] bf16

  mfma_layer<32, 32, 16, 16, 3, 1, 6, 5, true, 0, 0, WB_A1, 5120, PACKED>(wp, aw1, ab1, rs, a1, tid);
  if (tid < 4) *(uint2*)(a1 + 2560 + tid*8) = z2;
  __syncthreads();
  mfma_layer<16, 16,  8,  8, 2, 1, 5,-1, true, 0, 0, WB_A2, 2560, PACKED>(wp, aw2, ab2, a1, a2, tid);
  if (tid < 4) *(uint2*)(a2 + 1280 + tid*8) = z2;
  __syncthreads();
  mfma_layer< 8,  8,  4,  8, 1, 1,-1,-1, true, 0, 0, WB_A3, 1280, PACKED>(wp, aw3, ab3, a2, a3, tid);
  if (tid < 4) *(uint2*)(a3 + 1280 + tid*8) = z2;
  __syncthreads();
  mfma_layer< 8,  4,  2,  8, 1, 1,-1,-1, true, 0, 0, WB_A4, 1280, PACKED>(wp, aw4, ab4, a3, a4, tid);
  if (tid < 4) *(uint2*)(a4 + 1280 + tid*8) = z2;
  __syncthreads();
  mfma_layer< 8,  2,  1,  1, 1, 1,-1,-1, true, 3, 0, WB_A5, 1280, PACKED>(wp, aw5, ab5, a4, a5, tid);
  __syncthreads();

  // logits[b][o] = lb[o] + sum_t a5[b][t] * lw[o][t]
  if (p < 9){
    float acc = lb[p];
    #pragma unroll
    for (int t = 0; t < 9; ++t)
      acc = fmaf(lw[p*9 + t], bf2f(*(const unsigned short*)(a5 + (bl*9 + t)*2)), acc);
    logits_s[bl*9 + p] = acc;
  }
  __syncthreads();

  if (p == 0){
    float m = -1e30f;
    #pragma unroll
    for (int t = 0; t < 9; ++t) m = fmaxf(m, logits_s[bl*9 + t]);
    float s = 0.f, ex[9];
    #pragma unroll
    for (int t = 0; t < 9; ++t){ ex[t] = __expf(logits_s[bl*9 + t] - m); s += ex[t]; }
    float inv = 1.f / s;
    #pragma unroll
    for (int t = 0; t < 9; ++t) att_s[bl*9 + t] = ex[t]*inv;
  }
  __syncthreads();

  // sub[b][s] = sum_t rs[b][s][t] * att[b][t]   (rs flat [R][32] swz6)
  {
    int s = p;
    float acc = 0.f;
    #pragma unroll
    for (int t = 0; t < 9; ++t){
      unsigned byte = (unsigned)(((bl*9 + t)*32 + s)*2);
      acc = fmaf(bf2f(*(const unsigned short*)(rs + swz<6>(byte))), att_s[bl*9 + t], acc);
    }
    sub_s[bl*32 + s] = acc;
  }
  __syncthreads();

  // out[b][e] = 10 * sum_s mapping[id[b]][e][s] * sub[b][s]
  {
    const int b = b0 + bl;
    const size_t id = (size_t)ident[b];
    const float* mb = mapping + id*53*32;
    const float* subp = &sub_s[bl*32];
    for (int e = p; e < 53; e += 32){
      const float4* mrow4 = (const float4*)(mb + e*32);
      float acc = 0.f;
      #pragma unroll
      for (int s4 = 0; s4 < 8; ++s4){
        float4 mv = mrow4[s4];
        acc = fmaf(mv.x, subp[s4*4+0], acc);
        acc = fmaf(mv.y, subp[s4*4+1], acc);
        acc = fmaf(mv.z, subp[s4*4+2], acc);
        acc = fmaf(mv.w, subp[s4*4+3], acc);
      }
      out[(size_t)b*53 + e] = 10.f*acc;
    }
  }
}

extern "C" void kernel_launch(void* const* d_in, const int* in_sizes, int n_in,
                              void* d_out, int out_size, void* d_ws, size_t ws_size,
                              hipStream_t stream) {
  const float* x    = (const float*)d_in[0];
  const int*   ident= (const int*)  d_in[1];
  const float* cw1  = (const float*)d_in[2];  const float* cb1 = (const float*)d_in[3];
  const float* cw2  = (const float*)d_in[4];  const float* cb2 = (const float*)d_in[5];
  const float* cw3  = (const float*)d_in[6];  const float* cb3 = (const float*)d_in[7];
  const float* cw4  = (const float*)d_in[8];  const float* cb4 = (const float*)d_in[9];
  const float* fw1  = (const float*)d_in[10]; const float* fb1 = (const float*)d_in[11];
  const float* fw2  = (const float*)d_in[12]; const float* fb2 = (const float*)d_in[13];
  const float* fw3  = (const float*)d_in[14]; const float* fb3 = (const float*)d_in[15];
  const float* aw1  = (const float*)d_in[16]; const float* ab1 = (const float*)d_in[17];
  const float* aw2  = (const float*)d_in[18]; const float* ab2 = (const float*)d_in[19];
  const float* aw3  = (const float*)d_in[20]; const float* ab3 = (const float*)d_in[21];
  const float* aw4  = (const float*)d_in[22]; const float* ab4 = (const float*)d_in[23];
  const float* aw5  = (const float*)d_in[24]; const float* ab5 = (const float*)d_in[25];
  const float* lw   = (const float*)d_in[26]; const float* lb  = (const float*)d_in[27];
  const float* mapping = (const float*)d_in[28];

  const int B = 32768;
  dim3 grid(B / NB), block(THREADS);

  const bool packed = ws_size >= (size_t)(WP_TOTAL * 2);
  short* wpk = (short*)d_ws;

  if (packed){
    pack_weights<<<dim3(WP_TOTAL/256), dim3(256), 0, stream>>>(
        cw1, cw2, cw3, cw4, fw1, fw2, fw3, aw1, aw2, aw3, aw4, aw5, wpk);
    fused_expr_kernel<true><<<grid, block, 0, stream>>>(
        x, ident, cw1, cb1, cw2, cb2, cw3, cb3, cw4, cb4,
        fw1, fb1, fw2, fb2, fw3, fb3,
        aw1, ab1, aw2, ab2, aw3, ab3, aw4, ab4, aw5, ab5,
        lw, lb, mapping, wpk, (float*)d_out);
  } else {
    fused_expr_kernel<false><<<grid, block, 0, stream>>>(
        x, ident, cw1, cb1, cw2, cb2, cw3, cb3, cw4, cb4,
        fw1, fb1, fw2, fb2, fw3, fb3,
        aw1, ab1, aw2, ab2, aw3, ab3, aw4, ab4, aw5, ab5,
        lw, lb, mapping, wpk, (float*)d_out);
  }
}